// Round 1
// baseline (11418.940 us; speedup 1.0000x reference)
//
#include <hip/hip_runtime.h>
#include <cstdint>
#include <cstddef>

#define T_STEPS 2048
#define BATCH 64

typedef _Float16 f16;
typedef _Float16 f16x2 __attribute__((ext_vector_type(2)));
typedef _Float16 f16x8 __attribute__((ext_vector_type(8)));
typedef float f32x4 __attribute__((ext_vector_type(4)));
typedef unsigned int uint32;

__device__ __forceinline__ float dot2(uint32 w, uint32 h, float c) {
  f16x2 a = __builtin_bit_cast(f16x2, w);
  f16x2 b = __builtin_bit_cast(f16x2, h);
  return __builtin_amdgcn_fdot2(a, b, c, false);
}

__device__ __forceinline__ uint32 pack2(f16 a, f16 b) {
  f16x2 t; t[0] = a; t[1] = b;
  return __builtin_bit_cast(uint32, t);
}

// ---------------------------------------------------------------- setup ----
__global__ __launch_bounds__(256) void setup_weights(
    const float* __restrict__ Wf, const float* __restrict__ Wi,
    const float* __restrict__ Wo, const float* __restrict__ Wc,
    const float* __restrict__ bf, const float* __restrict__ bi,
    const float* __restrict__ bo, const float* __restrict__ bc,
    const float* __restrict__ Wout,
    f16* __restrict__ wx16, f16* __restrict__ wout16,
    uint32* __restrict__ whs, float* __restrict__ biasAll)
{
  int id = blockIdx.x * 256 + threadIdx.x;
  const float* WG_[4] = {Wf, Wi, Wo, Wc};
  const float* bG_[4] = {bf, bi, bo, bc};
  if (id < 262144) {                       // WxAll f16 [1024][256] (x-part cols)
    int n = id >> 8, k = id & 255;
    int G = n >> 8, j = n & 255;
    wx16[id] = (f16)WG_[G][j * 512 + k];
    return;
  }
  id -= 262144;
  if (id < 65536) { wout16[id] = (f16)Wout[id]; return; }   // Wout f16 [256][256]
  id -= 65536;
  if (id < 131072) {                       // WhS: per-member streamed layout
    int s  = id >> 14;
    int r2 = id & 16383;
    int k2b = r2 >> 9;
    int r3  = r2 & 511;
    int nl = r3 >> 2, kk = r3 & 3;
    int k2 = k2b * 4 + kk;
    int G = nl >> 5, jj = nl & 31;
    int j = s * 32 + jj;
    const float* WG = WG_[G];
    f16 v0 = (f16)WG[j * 512 + 256 + 2 * k2];
    f16 v1 = (f16)WG[j * 512 + 256 + 2 * k2 + 1];
    whs[s * 16384 + (k2b * 128 + nl) * 4 + kk] = pack2(v0, v1);
    return;
  }
  id -= 131072;
  if (id < 1024) {                          // biasAll fp32 [1024]
    int G = id >> 8, j = id & 255;
    biasAll[id] = bG_[G][j];
  }
}

__global__ __launch_bounds__(256) void setup_state(
    const float* __restrict__ h0, const float* __restrict__ C0,
    f16* __restrict__ hx, float* __restrict__ c32, uint32* __restrict__ ctr)
{
  int id = blockIdx.x * 256 + threadIdx.x;
  if (id < 16384) { hx[id] = (f16)h0[id]; return; }
  id -= 16384;
  if (id < 16384) { c32[id] = C0[id]; return; }
  id -= 16384;
  if (id < 8) ctr[id] = 0;
}

// ---------------------------------------------------------------- GEMM -----
// C[M,N] = A[M,256] @ B[N,256]^T ; 128x128 tile, whole K staged, f16 MFMA.
template<int A_F32, int OUT_F32_BIAS>
__global__ __launch_bounds__(256) void gemm_k(
    const void* __restrict__ Av, const f16* __restrict__ B,
    void* __restrict__ Cv, const float* __restrict__ bias, int N)
{
  constexpr int LDA = 264;   // 256 + 8 pad (keeps 16B align, breaks bank conflicts)
  __shared__ f16 As[128 * 264];
  __shared__ f16 Bs[128 * 264];
  const int tid = threadIdx.x;
  const int m0 = blockIdx.x * 128;
  const int n0 = blockIdx.y * 128;

  if (A_F32) {
    const float* A = (const float*)Av;
    #pragma unroll
    for (int j = 0; j < 32; ++j) {
      int flat = (tid + j * 256) * 4;
      int row = flat >> 8, col = flat & 255;
      const float4 v = *(const float4*)(A + (size_t)(m0 + row) * 256 + col);
      uint2 u; u.x = pack2((f16)v.x, (f16)v.y); u.y = pack2((f16)v.z, (f16)v.w);
      *(uint2*)&As[row * LDA + col] = u;
    }
  } else {
    const f16* A = (const f16*)Av;
    #pragma unroll
    for (int j = 0; j < 32; ++j) {
      int flat = (tid + j * 256) * 4;
      int row = flat >> 8, col = flat & 255;
      *(uint2*)&As[row * LDA + col] = *(const uint2*)(A + (size_t)(m0 + row) * 256 + col);
    }
  }
  #pragma unroll
  for (int j = 0; j < 32; ++j) {
    int flat = (tid + j * 256) * 4;
    int row = flat >> 8, col = flat & 255;
    *(uint2*)&Bs[row * LDA + col] = *(const uint2*)(B + (size_t)(n0 + row) * 256 + col);
  }
  __syncthreads();

  const int wave = tid >> 6, l = tid & 63;
  const int wr = wave >> 1, wc = wave & 1;
  const int lr = l & 15, lq = l >> 4;

  f32x4 acc[4][4] = {};
  #pragma unroll
  for (int kk = 0; kk < 8; ++kk) {
    f16x8 a[4], b[4];
    #pragma unroll
    for (int mi = 0; mi < 4; ++mi)
      a[mi] = *(const f16x8*)&As[(64 * wr + 16 * mi + lr) * LDA + kk * 32 + lq * 8];
    #pragma unroll
    for (int ni = 0; ni < 4; ++ni)
      b[ni] = *(const f16x8*)&Bs[(64 * wc + 16 * ni + lr) * LDA + kk * 32 + lq * 8];
    #pragma unroll
    for (int mi = 0; mi < 4; ++mi)
      #pragma unroll
      for (int ni = 0; ni < 4; ++ni)
        acc[mi][ni] = __builtin_amdgcn_mfma_f32_16x16x32_f16(a[mi], b[ni], acc[mi][ni], 0, 0, 0);
  }

  #pragma unroll
  for (int mi = 0; mi < 4; ++mi) {
    #pragma unroll
    for (int ni = 0; ni < 4; ++ni) {
      int col = n0 + 64 * wc + 16 * ni + lr;
      float bv = 0.f;
      if (OUT_F32_BIAS) bv = bias[col];
      #pragma unroll
      for (int v = 0; v < 4; ++v) {
        int row = m0 + 64 * wr + 16 * mi + lq * 4 + v;
        if (OUT_F32_BIAS) ((float*)Cv)[(size_t)row * N + col] = acc[mi][ni][v] + bv;
        else              ((f16*)Cv)[(size_t)row * N + col] = (f16)acc[mi][ni][v];
      }
    }
  }
}

// --------------------------------------------------------- persistent LSTM -
// 64 WGs = 8 groups x 8 members. Group g: batch rows 8g..8g+7.
// Member s: j-slice [32s,32s+32) of all 4 gates (128 gate outputs/row).
// One monotonic counter barrier per group per step (agent scope).
__global__ __launch_bounds__(512) void lstm_persist(
    const uint32* __restrict__ whs, const float* __restrict__ biasAll,
    const f16* __restrict__ xproj, f16* __restrict__ hx,
    float* __restrict__ c32g, uint32* __restrict__ ctr,
    float* __restrict__ hid_out, f16* __restrict__ h16c,
    float* __restrict__ cf_out, int t0, int Tc)
{
  __shared__ uint32 h2lds[1024];      // [8 rows][128 half2]
  __shared__ float  part[512 * 8];    // per-thread partial sums

  const int tid = threadIdx.x;
  const int g = blockIdx.x & 7;       // group (same XCD heuristic: members differ by 8)
  const int s = blockIdx.x >> 3;      // member
  const int q  = tid >> 7;            // k-quarter (K-split across 4 thread groups)
  const int nl = tid & 127;           // gate-local output index (G*32+jj)

  const int urow = tid >> 5;          // update-thread mapping (tid<256)
  const int ujj  = tid & 31;
  const int brow = 8 * g + urow;
  const int jg   = 32 * s + ujj;

  const uint32* wbase = whs + s * 16384;
  const uint32* hxu = (const uint32*)hx;

  float Creg = 0.f;
  float bias4[4] = {0.f, 0.f, 0.f, 0.f};
  if (tid < 256) {
    Creg = c32g[brow * 256 + jg];
    #pragma unroll
    for (int G = 0; G < 4; ++G) bias4[G] = biasAll[G * 256 + jg];
  }

  for (int tl = 0; tl < Tc; ++tl) {
    const int gt = t0 + tl;
    const int pp = gt & 1;

    // prefetch x-projection (independent of h) before waiting
    float xp[4] = {0.f, 0.f, 0.f, 0.f};
    if (tid < 256) {
      const f16* xrow = xproj + ((size_t)tl * 64 + brow) * 1024 + jg;
      #pragma unroll
      for (int G = 0; G < 4; ++G) xp[G] = (float)xrow[G * 256];
    }

    // wait until all 8 members finished step gt-1 (monotonic, no reset)
    if (tid == 0) {
      const uint32 target = 8u * (uint32)gt;
      while (__hip_atomic_load(ctr + g, __ATOMIC_RELAXED, __HIP_MEMORY_SCOPE_AGENT) < target)
        __builtin_amdgcn_s_sleep(1);
      __builtin_amdgcn_fence(__ATOMIC_ACQUIRE, "agent");
    }
    __syncthreads();

    // stage group's h (8 rows x 256 f16) into LDS
    {
      const uint32* src = hxu + pp * 8192 + g * 1024;
      h2lds[tid]       = src[tid];
      h2lds[tid + 512] = src[tid + 512];
    }
    __syncthreads();

    // recurrent matmul partials: this thread's k-quarter, all 8 rows
    float acc[8] __attribute__((aligned(16))) = {};
    #pragma unroll
    for (int kb = 0; kb < 8; ++kb) {
      const int k2b = q * 8 + kb;
      const uint4 w = *(const uint4*)(wbase + (size_t)(k2b * 128 + nl) * 4);
      #pragma unroll
      for (int r = 0; r < 8; ++r) {
        const uint4 hh = *(const uint4*)&h2lds[r * 128 + k2b * 4];
        acc[r] = dot2(w.x, hh.x, acc[r]);
        acc[r] = dot2(w.y, hh.y, acc[r]);
        acc[r] = dot2(w.z, hh.z, acc[r]);
        acc[r] = dot2(w.w, hh.w, acc[r]);
      }
    }
    {
      float* p = &part[tid * 8];
      *(f32x4*)p       = *(const f32x4*)acc;
      *(f32x4*)(p + 4) = *(const f32x4*)(acc + 4);
    }
    __syncthreads();

    // reduce + LSTM update (256 threads own one (row, j) each)
    if (tid < 256) {
      float pre[4];
      #pragma unroll
      for (int G = 0; G < 4; ++G) {
        const int nlg = G * 32 + ujj;
        float v = part[(0 * 128 + nlg) * 8 + urow]
                + part[(1 * 128 + nlg) * 8 + urow]
                + part[(2 * 128 + nlg) * 8 + urow]
                + part[(3 * 128 + nlg) * 8 + urow];
        pre[G] = v + xp[G] + bias4[G];
      }
      const float f_ = 1.f / (1.f + __expf(-pre[0]));
      const float i_ = 1.f / (1.f + __expf(-pre[1]));
      const float o_ = 1.f / (1.f + __expf(-pre[2]));
      const float cb = tanhf(pre[3]);
      const float Cn = f_ * Creg + i_ * cb;
      Creg = Cn;
      const float hn = o_ * tanhf(Cn);
      hid_out[((size_t)gt * 64 + brow) * 256 + jg] = hn;
      const f16 h16 = (f16)hn;
      hx[(pp ^ 1) * 16384 + brow * 256 + jg] = h16;
      h16c[((size_t)tl * 64 + brow) * 256 + jg] = h16;
      if (gt == T_STEPS - 1) cf_out[brow * 256 + jg] = Cn;
    }
    __syncthreads();
    if (tid == 0)
      __hip_atomic_fetch_add(ctr + g, 1u, __ATOMIC_RELEASE, __HIP_MEMORY_SCOPE_AGENT);
  }

  if (tid < 256) c32g[brow * 256 + jg] = Creg;
}

// ---------------------------------------------------------------- host -----
extern "C" void kernel_launch(void* const* d_in, const int* in_sizes, int n_in,
                              void* d_out, int out_size, void* d_ws, size_t ws_size,
                              hipStream_t stream)
{
  const float* x    = (const float*)d_in[0];
  const float* h0   = (const float*)d_in[1];
  const float* C0   = (const float*)d_in[2];
  const float* Wf   = (const float*)d_in[3];
  const float* bf   = (const float*)d_in[4];
  const float* Wi   = (const float*)d_in[5];
  const float* bi   = (const float*)d_in[6];
  const float* Wo   = (const float*)d_in[7];
  const float* bo   = (const float*)d_in[8];
  const float* Wc   = (const float*)d_in[9];
  const float* bc   = (const float*)d_in[10];
  const float* Wout = (const float*)d_in[11];
  const float* bout = (const float*)d_in[12];
  float* out = (float*)d_out;

  char* w = (char*)d_ws;
  f16*    wx16    = (f16*)w;    w += (size_t)1024 * 256 * 2;
  f16*    wout16  = (f16*)w;    w += (size_t)256 * 256 * 2;
  uint32* whs     = (uint32*)w; w += (size_t)131072 * 4;
  float*  biasAll = (float*)w;  w += (size_t)1024 * 4;
  f16*    hx      = (f16*)w;    w += (size_t)2 * 64 * 256 * 2;
  float*  c32     = (float*)w;  w += (size_t)64 * 256 * 4;
  uint32* ctr     = (uint32*)w; w += 256;
  const size_t fixedB = (size_t)(w - (char*)d_ws);

  int Tc = 2;
  const int cands[] = {2048, 1024, 512, 256, 128, 64, 32, 16, 8, 4, 2};
  for (int c : cands) {
    if (fixedB + (size_t)c * 163840 <= ws_size) { Tc = c; break; }
  }

  f16* xproj = (f16*)w;
  f16* h16c  = (f16*)(w + (size_t)Tc * 64 * 1024 * 2);

  setup_weights<<<1796, 256, 0, stream>>>(Wf, Wi, Wo, Wc, bf, bi, bo, bc, Wout,
                                          wx16, wout16, whs, biasAll);
  setup_state<<<129, 256, 0, stream>>>(h0, C0, hx, c32, ctr);

  float* hid_out = out + (size_t)T_STEPS * 64 * 256;
  float* cf_out  = out + (size_t)2 * T_STEPS * 64 * 256;

  for (int t0 = 0; t0 < T_STEPS; t0 += Tc) {
    gemm_k<1, 0><<<dim3(Tc * 64 / 128, 8), 256, 0, stream>>>(
        x + (size_t)t0 * 64 * 256, wx16, xproj, nullptr, 1024);
    lstm_persist<<<64, 512, 0, stream>>>(whs, biasAll, xproj, hx, c32, ctr,
                                         hid_out, h16c, cf_out, t0, Tc);
    gemm_k<0, 1><<<dim3(Tc * 64 / 128, 2), 256, 0, stream>>>(
        h16c, wout16, out + (size_t)t0 * 64 * 256, bout, 256);
  }
}

// Round 4
// 6875.948 us; speedup vs baseline: 1.6607x; 1.6607x over previous
//
#include <hip/hip_runtime.h>
#include <cstdint>
#include <cstddef>

#define T_STEPS 2048
#define BATCH 64

typedef _Float16 f16;
typedef _Float16 f16x2 __attribute__((ext_vector_type(2)));
typedef _Float16 f16x8 __attribute__((ext_vector_type(8)));
typedef float f32x4 __attribute__((ext_vector_type(4)));
typedef unsigned int uint32;
typedef unsigned long long uint64;
typedef uint32 u32x4 __attribute__((ext_vector_type(4)));

__device__ __forceinline__ float dot2(uint32 w, uint32 h, float c) {
  f16x2 a = __builtin_bit_cast(f16x2, w);
  f16x2 b = __builtin_bit_cast(f16x2, h);
  return __builtin_amdgcn_fdot2(a, b, c, false);
}

__device__ __forceinline__ uint32 pack2(f16 a, f16 b) {
  f16x2 t; t[0] = a; t[1] = b;
  return __builtin_bit_cast(uint32, t);
}

// ---------------------------------------------------------------- setup ----
__global__ __launch_bounds__(256) void setup_weights(
    const float* __restrict__ Wf, const float* __restrict__ Wi,
    const float* __restrict__ Wo, const float* __restrict__ Wc,
    const float* __restrict__ bf, const float* __restrict__ bi,
    const float* __restrict__ bo, const float* __restrict__ bc,
    const float* __restrict__ Wout,
    f16* __restrict__ wx16, f16* __restrict__ wout16, float* __restrict__ biasAll)
{
  int id = blockIdx.x * 256 + threadIdx.x;
  const float* WG_[4] = {Wf, Wi, Wo, Wc};
  const float* bG_[4] = {bf, bi, bo, bc};
  if (id < 262144) {                       // WxAll f16 [1024][256] (x-part cols)
    int n = id >> 8, k = id & 255;
    int G = n >> 8, j = n & 255;
    wx16[id] = (f16)WG_[G][j * 512 + k];
    return;
  }
  id -= 262144;
  if (id < 65536) { wout16[id] = (f16)Wout[id]; return; }   // Wout f16 [256][256]
  id -= 65536;
  if (id < 1024) {                          // biasAll fp32 [1024]
    int G = id >> 8, j = id & 255;
    biasAll[id] = bG_[G][j];
  }
}

__global__ __launch_bounds__(256) void setup_state(
    const float* __restrict__ h0, const float* __restrict__ C0,
    f16* __restrict__ hx, float* __restrict__ c32, uint32* __restrict__ ctr)
{
  int id = blockIdx.x * 256 + threadIdx.x;
  if (id < 16384) { hx[id] = (f16)h0[id]; return; }
  id -= 16384;
  if (id < 16384) { c32[id] = C0[id]; return; }
  id -= 16384;
  if (id < 4096) ctr[id] = 0;
}

// ---------------------------------------------------------------- GEMM -----
// C[M,N] = A[M,256] @ B[N,256]^T ; 128x128 tile, whole K staged, f16 MFMA.
template<int A_F32, int OUT_F32_BIAS>
__global__ __launch_bounds__(256) void gemm_k(
    const void* __restrict__ Av, const f16* __restrict__ B,
    void* __restrict__ Cv, const float* __restrict__ bias, int N)
{
  constexpr int LDA = 264;
  __shared__ f16 As[128 * 264];
  __shared__ f16 Bs[128 * 264];
  const int tid = threadIdx.x;
  const int m0 = blockIdx.x * 128;
  const int n0 = blockIdx.y * 128;

  if (A_F32) {
    const float* A = (const float*)Av;
    #pragma unroll
    for (int j = 0; j < 32; ++j) {
      int flat = (tid + j * 256) * 4;
      int row = flat >> 8, col = flat & 255;
      const float4 v = *(const float4*)(A + (size_t)(m0 + row) * 256 + col);
      uint2 u; u.x = pack2((f16)v.x, (f16)v.y); u.y = pack2((f16)v.z, (f16)v.w);
      *(uint2*)&As[row * LDA + col] = u;
    }
  } else {
    const f16* A = (const f16*)Av;
    #pragma unroll
    for (int j = 0; j < 32; ++j) {
      int flat = (tid + j * 256) * 4;
      int row = flat >> 8, col = flat & 255;
      *(uint2*)&As[row * LDA + col] = *(const uint2*)(A + (size_t)(m0 + row) * 256 + col);
    }
  }
  #pragma unroll
  for (int j = 0; j < 32; ++j) {
    int flat = (tid + j * 256) * 4;
    int row = flat >> 8, col = flat & 255;
    *(uint2*)&Bs[row * LDA + col] = *(const uint2*)(B + (size_t)(n0 + row) * 256 + col);
  }
  __syncthreads();

  const int wave = tid >> 6, l = tid & 63;
  const int wr = wave >> 1, wc = wave & 1;
  const int lr = l & 15, lq = l >> 4;

  f32x4 acc[4][4] = {};
  #pragma unroll
  for (int kk = 0; kk < 8; ++kk) {
    f16x8 a[4], b[4];
    #pragma unroll
    for (int mi = 0; mi < 4; ++mi)
      a[mi] = *(const f16x8*)&As[(64 * wr + 16 * mi + lr) * LDA + kk * 32 + lq * 8];
    #pragma unroll
    for (int ni = 0; ni < 4; ++ni)
      b[ni] = *(const f16x8*)&Bs[(64 * wc + 16 * ni + lr) * LDA + kk * 32 + lq * 8];
    #pragma unroll
    for (int mi = 0; mi < 4; ++mi)
      #pragma unroll
      for (int ni = 0; ni < 4; ++ni)
        acc[mi][ni] = __builtin_amdgcn_mfma_f32_16x16x32_f16(a[mi], b[ni], acc[mi][ni], 0, 0, 0);
  }

  #pragma unroll
  for (int mi = 0; mi < 4; ++mi) {
    #pragma unroll
    for (int ni = 0; ni < 4; ++ni) {
      int col = n0 + 64 * wc + 16 * ni + lr;
      float bv = 0.f;
      if (OUT_F32_BIAS) bv = bias[col];
      #pragma unroll
      for (int v = 0; v < 4; ++v) {
        int row = m0 + 64 * wr + 16 * mi + lq * 4 + v;
        if (OUT_F32_BIAS) ((float*)Cv)[(size_t)row * N + col] = acc[mi][ni][v] + bv;
        else              ((f16*)Cv)[(size_t)row * N + col] = (f16)acc[mi][ni][v];
      }
    }
  }
}

// --------------------------------------------------------- persistent LSTM -
// 64 WGs = 8 groups x 8 members. Group g: batch rows 8g..8g+7.
// Member s: j-slice [32s,32s+32) of all 4 gates. Weights register-resident.
// Exchange: ALL cross-WG traffic via __hip_atomic_* RELAXED AGENT ops
// (device-coherent, no cache-maintenance fences). Writer protocol:
//   wave0 atomic-stores h slice (64 x u64, single wave) -> s_waitcnt vmcnt(0)
//   (acks from coherence point) -> lane0 atomic-stores monotonic flag gt+1.
// Reader: spin relaxed-load 8 flags >= gt -> barrier -> atomic-load h.
__global__ __launch_bounds__(512) void lstm_persist(
    const float* __restrict__ Wf, const float* __restrict__ Wi,
    const float* __restrict__ Wo, const float* __restrict__ Wc,
    const float* __restrict__ biasAll,
    const f16* __restrict__ xproj, f16* __restrict__ hx,
    float* __restrict__ c32g, uint32* __restrict__ ctr,
    float* __restrict__ hid_out, f16* __restrict__ h16c,
    float* __restrict__ cf_out, int t0, int Tc)
{
  __shared__ uint32 h2lds[1024];      // group's h: [8 rows][128 u32]
  __shared__ float  part[8 * 516];    // [row][q*128+nl], pad 4 -> conflict-free
  __shared__ f16    hstage[256];      // member's new h slice [8 rows][32 j]

  const int tid  = threadIdx.x;
  const int wgid = blockIdx.x;
  const int g = wgid & 7;             // group
  const int s = wgid >> 3;            // member
  const int q  = tid >> 7;            // k-quarter
  const int nl = tid & 127;           // gate-local output index (G*32+jj)

  const int urow = tid >> 5;          // update mapping (tid<256)
  const int ujj  = tid & 31;
  const int brow = 8 * g + urow;
  const int jg   = 32 * s + ujj;

  uint64* hxu64 = (uint64*)hx;
  uint32* flagS = ctr + (g * 8 + s) * 64;   // this member's flag (256B spaced)

  // ---- preload recurrent weights into VGPRs (one-time) ----
  u32x4 wreg[8];
  {
    const int G = nl >> 5;
    const int j = s * 32 + (nl & 31);
    const float* WG = (G == 0) ? Wf : (G == 1) ? Wi : (G == 2) ? Wo : Wc;
    const float* wrow = WG + j * 512 + 256;
    #pragma unroll
    for (int kb = 0; kb < 8; ++kb) {
      const int k2b = q * 8 + kb;
      u32x4 wv;
      #pragma unroll
      for (int kk = 0; kk < 4; ++kk) {
        const float2 ab = *(const float2*)(wrow + 2 * (k2b * 4 + kk));
        wv[kk] = pack2((f16)ab.x, (f16)ab.y);
      }
      wreg[kb] = wv;
    }
  }

  float Creg = 0.f;
  float bias4[4] = {0.f, 0.f, 0.f, 0.f};
  if (tid < 256) {
    Creg = c32g[brow * 256 + jg];
    #pragma unroll
    for (int G = 0; G < 4; ++G) bias4[G] = biasAll[G * 256 + jg];
  }

  for (int tl = 0; tl < Tc; ++tl) {
    const int gt = t0 + tl;
    const int pp = gt & 1;

    // x-projection prefetch (plain cached loads; produced by earlier dispatch)
    float xp[4] = {0.f, 0.f, 0.f, 0.f};
    if (tid < 256) {
      const f16* xrow = xproj + ((size_t)tl * 64 + brow) * 1024 + jg;
      #pragma unroll
      for (int G = 0; G < 4; ++G) xp[G] = (float)xrow[G * 256];
    }

    // wait until all 8 members published step gt-1's h (flags >= gt)
    if (gt > 0 && tid < 8) {
      const uint32* fp = ctr + (g * 8 + tid) * 64;
      uint32 f = __hip_atomic_load(fp, __ATOMIC_RELAXED, __HIP_MEMORY_SCOPE_AGENT);
      int tries = 0;
      while (f < (uint32)gt && ++tries < (1 << 22)) {
        __builtin_amdgcn_s_sleep(1);
        f = __hip_atomic_load(fp, __ATOMIC_RELAXED, __HIP_MEMORY_SCOPE_AGENT);
      }
    }
    __syncthreads();

    // stage group's h (8 rows x 256 f16 = 4KB) into LDS via atomic loads
    if (tid < 256) {
      const uint64* src = hxu64 + (size_t)pp * 4096 + g * 512 + tid * 2;
      uint64 a = __hip_atomic_load(src,     __ATOMIC_RELAXED, __HIP_MEMORY_SCOPE_AGENT);
      uint64 b = __hip_atomic_load(src + 1, __ATOMIC_RELAXED, __HIP_MEMORY_SCOPE_AGENT);
      *(uint64*)&h2lds[tid * 4]     = a;
      *(uint64*)&h2lds[tid * 4 + 2] = b;
    }
    __syncthreads();

    // recurrent matmul partials: weights from VGPRs, h broadcast from LDS
    float acc[8] = {};
    #pragma unroll
    for (int kb = 0; kb < 8; ++kb) {
      const int k2b = q * 8 + kb;
      const u32x4 w = wreg[kb];
      #pragma unroll
      for (int r = 0; r < 8; ++r) {
        const u32x4 hh = *(const u32x4*)&h2lds[r * 128 + k2b * 4];
        acc[r] = dot2(w[0], hh[0], acc[r]);
        acc[r] = dot2(w[1], hh[1], acc[r]);
        acc[r] = dot2(w[2], hh[2], acc[r]);
        acc[r] = dot2(w[3], hh[3], acc[r]);
      }
    }
    #pragma unroll
    for (int r = 0; r < 8; ++r) part[r * 516 + tid] = acc[r];
    __syncthreads();

    // reduce + LSTM update (256 threads own one (row, j) each)
    if (tid < 256) {
      float pre[4];
      #pragma unroll
      for (int G = 0; G < 4; ++G) {
        const int c = G * 32 + ujj;
        const float* pr = &part[urow * 516 + c];
        pre[G] = pr[0] + pr[128] + pr[256] + pr[384] + xp[G] + bias4[G];
      }
      const float f_ = 1.f / (1.f + __expf(-pre[0]));
      const float i_ = 1.f / (1.f + __expf(-pre[1]));
      const float o_ = 1.f / (1.f + __expf(-pre[2]));
      const float cb = tanhf(pre[3]);
      const float Cn = f_ * Creg + i_ * cb;
      Creg = Cn;
      const float hn = o_ * tanhf(Cn);
      hid_out[((size_t)gt * 64 + brow) * 256 + jg] = hn;
      const f16 h16 = (f16)hn;
      hstage[urow * 32 + ujj] = h16;
      h16c[((size_t)tl * 64 + brow) * 256 + jg] = h16;
      if (gt == T_STEPS - 1) cf_out[brow * 256 + jg] = Cn;
    }
    __syncthreads();

    // publish: SINGLE wave (wave0) atomic-stores slice, vmcnt(0), then flag.
    if (tid < 64) {
      const uint64 v = ((const uint64*)hstage)[tid];
      const int row = tid >> 3;
      uint64* dst = hxu64 + (size_t)(pp ^ 1) * 4096 + (8 * g + row) * 64 + s * 8 + (tid & 7);
      __hip_atomic_store(dst, v, __ATOMIC_RELAXED, __HIP_MEMORY_SCOPE_AGENT);
      asm volatile("s_waitcnt vmcnt(0)" ::: "memory");
      if (tid == 0)
        __hip_atomic_store(flagS, (uint32)(gt + 1), __ATOMIC_RELAXED, __HIP_MEMORY_SCOPE_AGENT);
    }
  }

  if (tid < 256) c32g[brow * 256 + jg] = Creg;
}

// ---------------------------------------------------------------- host -----
extern "C" void kernel_launch(void* const* d_in, const int* in_sizes, int n_in,
                              void* d_out, int out_size, void* d_ws, size_t ws_size,
                              hipStream_t stream)
{
  const float* x    = (const float*)d_in[0];
  const float* h0   = (const float*)d_in[1];
  const float* C0   = (const float*)d_in[2];
  const float* Wf   = (const float*)d_in[3];
  const float* bf   = (const float*)d_in[4];
  const float* Wi   = (const float*)d_in[5];
  const float* bi   = (const float*)d_in[6];
  const float* Wo   = (const float*)d_in[7];
  const float* bo   = (const float*)d_in[8];
  const float* Wc   = (const float*)d_in[9];
  const float* bc   = (const float*)d_in[10];
  const float* Wout = (const float*)d_in[11];
  const float* bout = (const float*)d_in[12];
  float* out = (float*)d_out;

  char* w = (char*)d_ws;
  f16*    wx16    = (f16*)w;    w += (size_t)1024 * 256 * 2;
  f16*    wout16  = (f16*)w;    w += (size_t)256 * 256 * 2;
  float*  biasAll = (float*)w;  w += (size_t)1024 * 4;
  f16*    hx      = (f16*)w;    w += (size_t)2 * 64 * 256 * 2;
  float*  c32     = (float*)w;  w += (size_t)64 * 256 * 4;
  uint32* ctr     = (uint32*)w; w += 16384;   // flags: 64 x 256B spaced
  const size_t fixedB = (size_t)(w - (char*)d_ws);

  int Tc = 2;
  const int cands[] = {2048, 1024, 512, 256, 128, 64, 32, 16, 8, 4, 2};
  for (int c : cands) {
    if (fixedB + (size_t)c * 163840 <= ws_size) { Tc = c; break; }
  }

  f16* xproj = (f16*)w;
  f16* h16c  = (f16*)(w + (size_t)Tc * 64 * 1024 * 2);

  setup_weights<<<1284, 256, 0, stream>>>(Wf, Wi, Wo, Wc, bf, bi, bo, bc, Wout,
                                          wx16, wout16, biasAll);
  setup_state<<<144, 256, 0, stream>>>(h0, C0, hx, c32, ctr);

  float* hid_out = out + (size_t)T_STEPS * 64 * 256;
  float* cf_out  = out + (size_t)2 * T_STEPS * 64 * 256;

  for (int t0 = 0; t0 < T_STEPS; t0 += Tc) {
    gemm_k<1, 0><<<dim3(Tc * 64 / 128, 8), 256, 0, stream>>>(
        x + (size_t)t0 * 64 * 256, wx16, xproj, nullptr, 1024);
    lstm_persist<<<64, 512, 0, stream>>>(Wf, Wi, Wo, Wc, biasAll, xproj, hx, c32, ctr,
                                         hid_out, h16c, cf_out, t0, Tc);
    gemm_k<0, 1><<<dim3(Tc * 64 / 128, 2), 256, 0, stream>>>(
        h16c, wout16, out + (size_t)t0 * 64 * 256, bout, 256);
  }
}

// Round 7
// 4234.553 us; speedup vs baseline: 2.6966x; 1.6238x over previous
//
#include <hip/hip_runtime.h>
#include <cstdint>
#include <cstddef>

#define T_STEPS 2048
#define BATCH 64

typedef _Float16 f16;
typedef _Float16 f16x2 __attribute__((ext_vector_type(2)));
typedef _Float16 f16x8 __attribute__((ext_vector_type(8)));
typedef float f32x4 __attribute__((ext_vector_type(4)));
typedef unsigned int uint32;
typedef unsigned long long uint64;
typedef uint32 u32x4 __attribute__((ext_vector_type(4)));

__device__ __forceinline__ float dot2(uint32 w, uint32 h, float c) {
  f16x2 a = __builtin_bit_cast(f16x2, w);
  f16x2 b = __builtin_bit_cast(f16x2, h);
  return __builtin_amdgcn_fdot2(a, b, c, false);
}

__device__ __forceinline__ uint32 pack2(f16 a, f16 b) {
  f16x2 t; t[0] = a; t[1] = b;
  return __builtin_bit_cast(uint32, t);
}

// ---------------------------------------------------------------- setup ----
__global__ __launch_bounds__(256) void setup_weights(
    const float* __restrict__ Wf, const float* __restrict__ Wi,
    const float* __restrict__ Wo, const float* __restrict__ Wc,
    const float* __restrict__ Wout,
    f16* __restrict__ wx16, f16* __restrict__ wout16)
{
  int id = blockIdx.x * 256 + threadIdx.x;
  const float* WG_[4] = {Wf, Wi, Wo, Wc};
  if (id < 262144) {                       // WxAll f16 [1024][256] (x-part cols)
    int n = id >> 8, k = id & 255;
    int G = n >> 8, j = n & 255;
    wx16[id] = (f16)WG_[G][j * 512 + k];
    return;
  }
  id -= 262144;
  if (id < 65536) { wout16[id] = (f16)Wout[id]; return; }   // Wout f16 [256][256]
}

// hpair layout: [parity 2][slot 128 = row*2+half][64 u64]
// parity0 <- h0 tagged 0 ; parity1 <- sentinel tag 0xFFFF
__global__ __launch_bounds__(256) void setup_state(
    const float* __restrict__ h0, const float* __restrict__ C0,
    uint64* __restrict__ hpair, float* __restrict__ c32)
{
  int id = blockIdx.x * 256 + threadIdx.x;
  if (id < 8192) {                 // parity 0: tag0 | h0
    int slot = id >> 6, i = id & 63;
    int r = slot >> 1, hf = slot & 1;
    const float* hr = h0 + r * 256 + hf * 128 + 2 * i;
    uint32 a = (uint32)__builtin_bit_cast(unsigned short, (f16)hr[0]);
    uint32 b = (uint32)__builtin_bit_cast(unsigned short, (f16)hr[1]);
    hpair[id] = ((uint64)b << 32) | (uint64)a;
    return;
  }
  id -= 8192;
  if (id < 8192) {                 // parity 1: sentinel
    hpair[8192 + id] = 0xFFFF0000FFFF0000ULL;
    return;
  }
  id -= 8192;
  if (id < 16384) c32[id] = C0[id];
}

// ---------------------------------------------------------------- GEMM -----
// C[M,N] = A[M,256] @ B[N,256]^T ; 128x128 tile, whole K staged, f16 MFMA.
template<int A_F32, int OUT_F32_BIAS>
__global__ __launch_bounds__(256) void gemm_k(
    const void* __restrict__ Av, const f16* __restrict__ B,
    void* __restrict__ Cv, const float* __restrict__ bias, int N)
{
  constexpr int LDA = 264;
  __shared__ f16 As[128 * 264];
  __shared__ f16 Bs[128 * 264];
  const int tid = threadIdx.x;
  const int m0 = blockIdx.x * 128;
  const int n0 = blockIdx.y * 128;

  if (A_F32) {
    const float* A = (const float*)Av;
    #pragma unroll
    for (int j = 0; j < 32; ++j) {
      int flat = (tid + j * 256) * 4;
      int row = flat >> 8, col = flat & 255;
      const float4 v = *(const float4*)(A + (size_t)(m0 + row) * 256 + col);
      uint2 u; u.x = pack2((f16)v.x, (f16)v.y); u.y = pack2((f16)v.z, (f16)v.w);
      *(uint2*)&As[row * LDA + col] = u;
    }
  } else {
    const f16* A = (const f16*)Av;
    #pragma unroll
    for (int j = 0; j < 32; ++j) {
      int flat = (tid + j * 256) * 4;
      int row = flat >> 8, col = flat & 255;
      *(uint2*)&As[row * LDA + col] = *(const uint2*)(A + (size_t)(m0 + row) * 256 + col);
    }
  }
  #pragma unroll
  for (int j = 0; j < 32; ++j) {
    int flat = (tid + j * 256) * 4;
    int row = flat >> 8, col = flat & 255;
    *(uint2*)&Bs[row * LDA + col] = *(const uint2*)(B + (size_t)(n0 + row) * 256 + col);
  }
  __syncthreads();

  const int wave = tid >> 6, l = tid & 63;
  const int wr = wave >> 1, wc = wave & 1;
  const int lr = l & 15, lq = l >> 4;

  f32x4 acc[4][4] = {};
  #pragma unroll
  for (int kk = 0; kk < 8; ++kk) {
    f16x8 a[4], b[4];
    #pragma unroll
    for (int mi = 0; mi < 4; ++mi)
      a[mi] = *(const f16x8*)&As[(64 * wr + 16 * mi + lr) * LDA + kk * 32 + lq * 8];
    #pragma unroll
    for (int ni = 0; ni < 4; ++ni)
      b[ni] = *(const f16x8*)&Bs[(64 * wc + 16 * ni + lr) * LDA + kk * 32 + lq * 8];
    #pragma unroll
    for (int mi = 0; mi < 4; ++mi)
      #pragma unroll
      for (int ni = 0; ni < 4; ++ni)
        acc[mi][ni] = __builtin_amdgcn_mfma_f32_16x16x32_f16(a[mi], b[ni], acc[mi][ni], 0, 0, 0);
  }

  #pragma unroll
  for (int mi = 0; mi < 4; ++mi) {
    #pragma unroll
    for (int ni = 0; ni < 4; ++ni) {
      int col = n0 + 64 * wc + 16 * ni + lr;
      float bv = 0.f;
      if (OUT_F32_BIAS) bv = bias[col];
      #pragma unroll
      for (int v = 0; v < 4; ++v) {
        int row = m0 + 64 * wr + 16 * mi + lq * 4 + v;
        if (OUT_F32_BIAS) ((float*)Cv)[(size_t)row * N + col] = acc[mi][ni][v] + bv;
        else              ((f16*)Cv)[(size_t)row * N + col] = (f16)acc[mi][ni][v];
      }
    }
  }
}

// --------------------------------------------------------- persistent LSTM -
// 128 WGs x 512 thr. WG w: row r = w>>1, half hf = w&1. Thread owns ONE gate
// output (G=tid>>7, jj=tid&127) with FULL K=256 in 128 VGPRs.
// Exchange with the single sibling WG via tag-embedded atomic u64 words:
//   u32 word = (step_tag << 16) | f16 bits ; u64 store = 2 words, atomic.
// Writer fires 64 u64 stores and continues. Reader spins until both tags==gt.
// R6 bugfix: at tl==0 the OWN half of h_lds was never initialized (phase H
// of the previous iteration normally maintains it). Threads 64..127 now load
// it from mybuf (parity t0&1 carries tag t0: setup for t0=0, previous
// launch's phase H otherwise).
__global__ __launch_bounds__(512, 2) void lstm_persist(
    const float* __restrict__ Wf, const float* __restrict__ Wi,
    const float* __restrict__ Wo, const float* __restrict__ Wc,
    const float* __restrict__ bf, const float* __restrict__ bi,
    const float* __restrict__ bo, const float* __restrict__ bc,
    const f16* __restrict__ xproj, uint64* __restrict__ hpair,
    float* __restrict__ c32, float* __restrict__ hid_out,
    f16* __restrict__ h16c, float* __restrict__ cf_out, int t0, int Tc)
{
  __shared__ uint32 h_lds[128];            // full h: [half0 64 u32][half1 64 u32]
  __shared__ float  part[4 * 132];         // gate pre-acts, padded
  __shared__ unsigned short hstage[128];   // new own-half h (f16 bits)

  const int tid = threadIdx.x;
  const int w = blockIdx.x;
  const int r = w >> 1, hf = w & 1;
  const int G = tid >> 7, jj = tid & 127;
  const int j = hf * 128 + jj;

  // ---- one-time: weights for output (G,j), h-part, f32 -> f16 pairs ----
  u32x4 wreg[32];
  {
    const float* WG = (G == 0) ? Wf : (G == 1) ? Wi : (G == 2) ? Wo : Wc;
    const float* wrow = WG + (size_t)j * 512 + 256;
    #pragma unroll
    for (int kb = 0; kb < 32; ++kb) {
      u32x4 wv;
      #pragma unroll
      for (int kk = 0; kk < 4; ++kk) {
        const float2 ab = *(const float2*)(wrow + kb * 8 + kk * 2);
        wv[kk] = pack2((f16)ab.x, (f16)ab.y);
      }
      wreg[kb] = wv;
    }
  }
  const float* bG = (G == 0) ? bf : (G == 1) ? bi : (G == 2) ? bo : bc;
  const float biasv = bG[j];

  float Creg = 0.f;
  if (tid < 128) Creg = c32[r * 256 + hf * 128 + tid];

  uint64* mybuf  = hpair + (size_t)(r * 2 + hf) * 64;
  uint64* sibbuf = hpair + (size_t)(r * 2 + (hf ^ 1)) * 64;

  for (int tl = 0; tl < Tc; ++tl) {
    const int gt = t0 + tl;

    // A: x-projection prefetch (cached; hides under the spin)
    const float xpv = (float)xproj[((size_t)tl * 64 + r) * 1024 + (G << 8) + j];

    // B: fill h_lds. Sibling half: tag-validated spin (tid<64). Own half:
    // maintained by phase H, except at tl==0 where threads 64..127 load it.
    if (tid < 64) {
      const uint64* p = sibbuf + (size_t)(gt & 1) * 8192 + tid;
      const uint32 tg = (uint32)gt;
      uint64 v = __hip_atomic_load(p, __ATOMIC_RELAXED, __HIP_MEMORY_SCOPE_AGENT);
      int tries = 0;
      while (((((uint32)v) >> 16) != tg || ((uint32)(v >> 48)) != tg) &&
             ++tries < (1 << 22)) {
        v = __hip_atomic_load(p, __ATOMIC_RELAXED, __HIP_MEMORY_SCOPE_AGENT);
      }
      h_lds[(hf ^ 1) * 64 + tid] =
          (((uint32)v) & 0xFFFFu) | ((((uint32)(v >> 32)) & 0xFFFFu) << 16);
    } else if (tl == 0 && tid < 128) {
      const int i = tid - 64;
      const uint64* p = mybuf + (size_t)(gt & 1) * 8192 + i;
      const uint32 tg = (uint32)gt;
      uint64 v = __hip_atomic_load(p, __ATOMIC_RELAXED, __HIP_MEMORY_SCOPE_AGENT);
      int tries = 0;
      while (((((uint32)v) >> 16) != tg || ((uint32)(v >> 48)) != tg) &&
             ++tries < (1 << 22)) {
        v = __hip_atomic_load(p, __ATOMIC_RELAXED, __HIP_MEMORY_SCOPE_AGENT);
      }
      h_lds[hf * 64 + i] =
          (((uint32)v) & 0xFFFFu) | ((((uint32)(v >> 32)) & 0xFFFFu) << 16);
    }
    __syncthreads();  // C

    // D: full-K dot-product chain (weights in VGPRs, h broadcast from LDS)
    float acc = xpv + biasv;
    #pragma unroll
    for (int kb = 0; kb < 32; ++kb) {
      const u32x4 hh = *(const u32x4*)&h_lds[kb * 4];
      const u32x4 wv = wreg[kb];
      acc = dot2(wv[0], hh[0], acc);
      acc = dot2(wv[1], hh[1], acc);
      acc = dot2(wv[2], hh[2], acc);
      acc = dot2(wv[3], hh[3], acc);
    }
    part[G * 132 + jj] = acc;
    __syncthreads();  // E

    // F: LSTM pointwise update (own 128 j's)
    if (tid < 128) {
      const float pf = part[0 * 132 + tid];
      const float pi = part[1 * 132 + tid];
      const float po = part[2 * 132 + tid];
      const float pc = part[3 * 132 + tid];
      const float f_ = 1.f / (1.f + __expf(-pf));
      const float i_ = 1.f / (1.f + __expf(-pi));
      const float o_ = 1.f / (1.f + __expf(-po));
      const float cb = tanhf(pc);
      const float Cn = f_ * Creg + i_ * cb;
      Creg = Cn;
      const float hn = o_ * tanhf(Cn);
      const int jglob = hf * 128 + tid;
      hid_out[((size_t)gt * 64 + r) * 256 + jglob] = hn;
      const f16 h16v = (f16)hn;
      hstage[tid] = __builtin_bit_cast(unsigned short, h16v);
      h16c[((size_t)tl * 64 + r) * 256 + jglob] = h16v;
      if (gt == T_STEPS - 1) cf_out[r * 256 + jglob] = Cn;
    }
    __syncthreads();  // G

    // H: publish own half (fire-and-go atomic u64 tagged stores) + local h
    if (tid < 64) {
      const uint32 a = (uint32)hstage[2 * tid];
      const uint32 b = (uint32)hstage[2 * tid + 1];
      h_lds[hf * 64 + tid] = a | (b << 16);
      const uint32 tg1u = ((uint32)(gt + 1)) << 16;
      const uint64 v = ((uint64)(b | tg1u) << 32) | (uint64)(a | tg1u);
      __hip_atomic_store(mybuf + (size_t)((gt + 1) & 1) * 8192 + tid, v,
                         __ATOMIC_RELAXED, __HIP_MEMORY_SCOPE_AGENT);
    }
  }

  if (tid < 128) c32[r * 256 + hf * 128 + tid] = Creg;
}

// ---------------------------------------------------------------- host -----
extern "C" void kernel_launch(void* const* d_in, const int* in_sizes, int n_in,
                              void* d_out, int out_size, void* d_ws, size_t ws_size,
                              hipStream_t stream)
{
  const float* x    = (const float*)d_in[0];
  const float* h0   = (const float*)d_in[1];
  const float* C0   = (const float*)d_in[2];
  const float* Wf   = (const float*)d_in[3];
  const float* bf   = (const float*)d_in[4];
  const float* Wi   = (const float*)d_in[5];
  const float* bi   = (const float*)d_in[6];
  const float* Wo   = (const float*)d_in[7];
  const float* bo   = (const float*)d_in[8];
  const float* Wc   = (const float*)d_in[9];
  const float* bc   = (const float*)d_in[10];
  const float* Wout = (const float*)d_in[11];
  const float* bout = (const float*)d_in[12];
  float* out = (float*)d_out;

  char* w = (char*)d_ws;
  f16*    wx16   = (f16*)w;    w += (size_t)1024 * 256 * 2;
  f16*    wout16 = (f16*)w;    w += (size_t)256 * 256 * 2;
  uint64* hpair  = (uint64*)w; w += (size_t)2 * 8192 * 8;   // 128KB
  float*  c32    = (float*)w;  w += (size_t)64 * 256 * 4;
  const size_t fixedB = (size_t)(w - (char*)d_ws);

  int Tc = 2;
  const int cands[] = {2048, 1024, 512, 256, 128, 64, 32, 16, 8, 4, 2};
  for (int c : cands) {
    if (fixedB + (size_t)c * 163840 <= ws_size) { Tc = c; break; }
  }

  f16* xproj = (f16*)w;
  f16* h16c  = (f16*)(w + (size_t)Tc * 64 * 1024 * 2);

  setup_weights<<<1280, 256, 0, stream>>>(Wf, Wi, Wo, Wc, Wout, wx16, wout16);
  setup_state<<<128, 256, 0, stream>>>(h0, C0, hpair, c32);

  float* hid_out = out + (size_t)T_STEPS * 64 * 256;
  float* cf_out  = out + (size_t)2 * T_STEPS * 64 * 256;

  for (int t0 = 0; t0 < T_STEPS; t0 += Tc) {
    gemm_k<1, 0><<<dim3(Tc * 64 / 128, 8), 256, 0, stream>>>(
        x + (size_t)t0 * 64 * 256, wx16, xproj, nullptr, 1024);
    lstm_persist<<<128, 512, 0, stream>>>(Wf, Wi, Wo, Wc, bf, bi, bo, bc,
                                          xproj, hpair, c32,
                                          hid_out, h16c, cf_out, t0, Tc);
    gemm_k<0, 1><<<dim3(Tc * 64 / 128, 2), 256, 0, stream>>>(
        h16c, wout16, out + (size_t)t0 * 64 * 256, bout, 256);
  }
}